// Round 4
// baseline (1940.588 us; speedup 1.0000x reference)
//
#include <hip/hip_runtime.h>
#include <stdint.h>

#define B_   256
#define NPG  512
#define NG   131072
#define EPG  4096
#define NQPG 16
#define NQ   4096
#define EQPG 128
#define L_   2

typedef __attribute__((ext_vector_type(8))) short short8;
typedef __attribute__((ext_vector_type(4))) float floatx4;

__device__ inline unsigned short f2bf(float f){
    union { float f; unsigned int i; } x; x.f = f;
    unsigned int r = x.i + 0x7fff + ((x.i >> 16) & 1);  // RNE
    return (unsigned short)(r >> 16);
}

// ---- transpose weights (fp32 in) to [N][K] bf16 ----
__global__ void k_transpose(const float* Wg, const float* Wq,
                            const float* W1r, const float* W2r,
                            unsigned short* WgT, unsigned short* WqT,
                            unsigned short* W1aT, unsigned short* W2rT){
    int idx = blockIdx.x*256 + threadIdx.x;
    if (idx < 8192){                       // Wg [64,128] -> WgT [128][64]
        int k = idx >> 7, n = idx & 127; WgT[n*64 + k] = f2bf(Wg[idx]);
    } else if (idx < 16384){
        int i = idx - 8192; int k = i>>7, n = i&127; WqT[n*64+k] = f2bf(Wq[i]);
    } else if (idx < 49152){               // W1r[l][0:128,:] -> W1aT[l][128][128]
        int i = idx - 16384; int l = i >> 14; int j = i & 16383; int k = j>>7, n = j&127;
        W1aT[l*16384 + n*128 + k] = f2bf(W1r[l*32768 + j]);
    } else {                               // W2r[l] [128,128] -> W2rT[l][128][128]
        int i = idx - 49152; int l = i >> 14; int j = i & 16383; int k = j>>7, n = j&127;
        W2rT[l*16384 + n*128 + k] = f2bf(W2r[i]);
    }
}

// ---- proj: out[M,128] = A_f32[M,64] @ WtT + bias ; out fp32 ----
__global__ __launch_bounds__(256) void k_proj(const float* __restrict__ A,
        const unsigned short* __restrict__ Wt, const float* __restrict__ bias,
        float* __restrict__ out){
    const int K = 64;
    int wave = threadIdx.x >> 6, lane = threadIdx.x & 63;
    int quad = lane >> 4, l16 = lane & 15;
    int wrow = blockIdx.x*64 + wave*16;
    floatx4 acc[8];
    #pragma unroll
    for (int t=0;t<8;t++){
        #pragma unroll
        for (int r=0;r<4;r++) acc[t][r]=0.f;
    }
    #pragma unroll
    for (int ks = 0; ks < 2; ks++){
        int koff = ks*32 + quad*8;
        const float* ap = A + (size_t)(wrow+l16)*K + koff;
        short8 a;
        #pragma unroll
        for (int j=0;j<8;j++) a[j] = (short)f2bf(ap[j]);
        #pragma unroll
        for (int t=0;t<8;t++){
            short8 b = *(const short8*)(Wt + (size_t)(t*16+l16)*K + koff);
            acc[t] = __builtin_amdgcn_mfma_f32_16x16x32_bf16(a, b, acc[t], 0,0,0);
        }
    }
    #pragma unroll
    for (int t=0;t<8;t++){
        int col = t*16 + l16;
        float bv = bias[col];
        #pragma unroll
        for (int r=0;r<4;r++){
            out[(size_t)(wrow + quad*4 + r)*128 + col] = acc[t][r] + bv;
        }
    }
}

// ---- query AGNN (fp32) + per-graph sum + Qg = ||hqa||^2 ----
__global__ __launch_bounds__(128) void k_qagnn(float* __restrict__ h_q,
        const int* __restrict__ q_src, const int* __restrict__ q_dst,
        const float* __restrict__ beta_p, float* __restrict__ hqa,
        float* __restrict__ Qg){
    int g = blockIdx.x, t = threadIdx.x;
    __shared__ float h[NQPG][132];
    __shared__ float e[EQPG], w[EQPG];
    __shared__ float inv[NQPG], mx[NQPG], den[NQPG];
    __shared__ int srcl[EQPG], dstl[EQPG], csr[EQPG];
    __shared__ int cnt[NQPG], off[NQPG], woff[NQPG];
    __shared__ float part[128];
    float beta = beta_p[0];
    for (int idx=t; idx<NQPG*128; idx+=128){
        int n = idx>>7, d = idx&127;
        h[n][d] = h_q[(size_t)(g*NQPG+n)*128 + d];
    }
    if (t<NQPG){ cnt[t]=0; mx[t]=0.f; den[t]=0.f; }
    __syncthreads();
    { int n=t>>3, c=t&7; float s=0;
      for (int d=c*16; d<c*16+16; d++){ float v=h[n][d]; s+=v*v; }
      part[t]=s; }
    __syncthreads();
    if (t<NQPG){ float s=0; for(int c=0;c<8;c++) s+=part[t*8+c]; inv[t]=rsqrtf(s+1e-24f); }
    __syncthreads();
    { int eidx = g*EQPG + t;
      int s = q_src[eidx] - g*NQPG, d = q_dst[eidx] - g*NQPG;
      srcl[t]=s; dstl[t]=d;
      float dot=0;
      for (int k=0;k<128;k++) dot += h[s][k]*h[d][k];
      e[t] = beta*dot*inv[s]*inv[d];
      atomicAdd(&cnt[d],1); }
    __syncthreads();
    if (t==0){ int o=0; for(int i=0;i<NQPG;i++){ off[i]=o; o+=cnt[i]; } }
    __syncthreads();
    if (t<NQPG){ woff[t]=off[t];
        if (cnt[t] > 0){
            float mm=-1e30f, dd=0.f;
            for (int j=0;j<EQPG;j++) if (dstl[j]==t) mm = fmaxf(mm, e[j]);
            for (int j=0;j<EQPG;j++) if (dstl[j]==t) dd += __expf(e[j]-mm);
            mx[t]=mm; den[t]=dd;
        } }
    __syncthreads();
    { int d = dstl[t];
      float dd = den[d];
      w[t] = dd > 0.f ? __expf(e[t]-mx[d]) / dd : 0.f;
      int pos = atomicAdd(&woff[d],1);
      csr[pos]=t; }
    __syncthreads();
    float aggr=0.f;
    { int d = t;
      for (int n=0;n<NQPG;n++){
          float acc=0.f;
          int o=off[n], c=cnt[n];
          for (int j=o;j<o+c;j++){ int ei=csr[j]; acc += w[ei]*h[srcl[ei]][d]; }
          h_q[(size_t)(g*NQPG+n)*128 + d] = acc;
          aggr += acc;
      }
      hqa[g*128+d]=aggr; }
    __syncthreads();
    part[t] = aggr*aggr;
    __syncthreads();
    for (int s2=64; s2>0; s2>>=1){
        if (t<s2) part[t]+=part[t+s2];
        __syncthreads();
    }
    if (t==0) Qg[g]=part[0];
}

// ---- per-graph cg2 = hqa @ W1r[l][128:256,:] (fp32) ----
__global__ __launch_bounds__(128) void k_cvec(const float* __restrict__ hqa,
        const float* __restrict__ W1r_l, float* __restrict__ cg2){
    int g = blockIdx.x, j = threadIdx.x;
    __shared__ float hq[128];
    hq[j] = hqa[g*128+j];
    __syncthreads();
    float acc = 0.f;
    for (int k=0;k<128;k++) acc += hq[k]*W1r_l[(128+k)*128 + j];
    cg2[g*128+j] = acc;
}

// ---- per-node squared norms of h_g (fp32) ----
__global__ __launch_bounds__(256) void k_norm(const float* __restrict__ h_g,
                                              float* __restrict__ nrm2){
    int wave = threadIdx.x>>6, lane = threadIdx.x&63;
    int node = blockIdx.x*4 + wave;
    float2 u = *(const float2*)(h_g + (size_t)node*128 + lane*2);
    float s = u.x*u.x + u.y*u.y;
    for (int o=32;o>0;o>>=1) s += __shfl_xor(s,o);
    if (lane==0) nrm2[node] = s;
}

// ---- data-graph AGNN over implicit h_cat; aout bf16 (MLP A-operand), degf ----
__global__ __launch_bounds__(256) void k_gagnn(const float* __restrict__ h_g,
        const float* __restrict__ nrm2, const float* __restrict__ Qg,
        const int* __restrict__ g_src, const int* __restrict__ g_dst,
        const float* __restrict__ beta_p,
        unsigned short* __restrict__ aout, float* __restrict__ degf){
    int g = blockIdx.x, t = threadIdx.x;
    int wave = t>>6, lane = t&63;
    __shared__ unsigned short srcl[EPG], dstl[EPG], csr[EPG];
    __shared__ float e[EPG];
    __shared__ float inv[NPG], mx[NPG], den[NPG];
    __shared__ int cnt[NPG], off[NPG], woff[NPG];
    float beta = beta_p[0];
    float Q = Qg[g];
    int gbase = g*NPG;
    for (int i=t; i<EPG; i+=256){
        srcl[i] = (unsigned short)(g_src[(size_t)g*EPG+i] - gbase);
        dstl[i] = (unsigned short)(g_dst[(size_t)g*EPG+i] - gbase);
    }
    for (int i=t; i<NPG; i+=256){
        inv[i] = rsqrtf(nrm2[gbase+i] + Q + 1e-24f);
        cnt[i]=0; mx[i]=0.f; den[i]=0.f;
    }
    __syncthreads();
    // edge logits: wave per edge; lane covers 2 dims
    for (int ei = wave; ei < EPG; ei += 4){
        int s = srcl[ei], d = dstl[ei];
        float2 us = *(const float2*)(h_g + (size_t)(gbase+s)*128 + lane*2);
        float2 ud = *(const float2*)(h_g + (size_t)(gbase+d)*128 + lane*2);
        float v = us.x*ud.x + us.y*ud.y;
        for (int o=32;o>0;o>>=1) v += __shfl_xor(v,o);
        if (lane==0){
            e[ei] = beta * (v + Q) * inv[s]*inv[d];
            atomicAdd(&cnt[d], 1);
        }
    }
    __syncthreads();
    if (t==0){ int o=0; for (int i=0;i<NPG;i++){ off[i]=o; o+=cnt[i]; } }
    __syncthreads();
    for (int i=t;i<NPG;i+=256) woff[i]=off[i];
    __syncthreads();
    for (int i=t;i<EPG;i+=256){
        int pos = atomicAdd(&woff[dstl[i]],1);
        csr[pos] = (unsigned short)i;
    }
    __syncthreads();
    for (int n=t;n<NPG;n+=256){
        int c=cnt[n];
        if (c > 0){
            int o=off[n];
            float mm=-1e30f;
            for (int j=0;j<c;j++) mm = fmaxf(mm, e[csr[o+j]]);
            float dd=0.f;
            for (int j=0;j<c;j++) dd += __expf(e[csr[o+j]]-mm);
            mx[n]=mm; den[n]=dd;
        }
    }
    __syncthreads();
    for (int i=t;i<EPG;i+=256){
        int d = dstl[i];
        float dd = den[d];
        e[i] = dd > 0.f ? __expf(e[i]-mx[d]) / dd : 0.f;
    }
    __syncthreads();
    // weighted gather (128-dim), wave per node
    for (int n=wave; n<NPG; n+=4){
        int c = cnt[n], o = off[n];
        float a0=0.f, a1=0.f;
        for (int j=0;j<c;j++){
            int ei = csr[o+j];
            int s = srcl[ei];
            float wg = e[ei];
            float2 us = *(const float2*)(h_g + (size_t)(gbase+s)*128 + lane*2);
            a0 += wg*us.x;
            a1 += wg*us.y;
        }
        unsigned int ov = (unsigned int)f2bf(a0) | ((unsigned int)f2bf(a1)<<16);
        *(unsigned int*)(aout + (size_t)(gbase+n)*128 + lane*2) = ov;
        if (lane==0) degf[gbase+n] = (c>0) ? 1.f : 0.f;
    }
}

// ---- fused MLP: h_g = relu(A@W1a + b1 + deg*cg2)@W2 + b2 (fp32 out) ----
__global__ __launch_bounds__(256) void k_mlp(const unsigned short* __restrict__ A,
        const unsigned short* __restrict__ W1t, const float* __restrict__ b1,
        const float* __restrict__ cg2, const float* __restrict__ degf,
        const unsigned short* __restrict__ W2t, const float* __restrict__ b2,
        float* __restrict__ out){
    __shared__ __align__(16) unsigned short h1[64*136];
    int wave = threadIdx.x>>6, lane = threadIdx.x&63;
    int quad = lane>>4, l16 = lane&15;
    int wrow = blockIdx.x*64 + wave*16;
    const float* cg = cg2 + (size_t)(blockIdx.x>>3)*128;
    floatx4 acc[8];
    #pragma unroll
    for (int t=0;t<8;t++){
        #pragma unroll
        for(int r=0;r<4;r++) acc[t][r]=0.f;
    }
    #pragma unroll
    for (int ks=0; ks<4; ks++){
        int koff = ks*32 + quad*8;
        short8 a = *(const short8*)(A + (size_t)(wrow+l16)*128 + koff);
        #pragma unroll
        for (int t=0;t<8;t++){
            short8 b = *(const short8*)(W1t + (size_t)(t*16+l16)*128 + koff);
            acc[t] = __builtin_amdgcn_mfma_f32_16x16x32_bf16(a,b,acc[t],0,0,0);
        }
    }
    float dg[4];
    #pragma unroll
    for (int r=0;r<4;r++) dg[r] = degf[wrow + quad*4 + r];
    #pragma unroll
    for (int t=0;t<8;t++){
        int col = t*16+l16;
        float bv = b1[col];
        float cv = cg[col];
        #pragma unroll
        for (int r=0;r<4;r++){
            float v = acc[t][r] + bv + dg[r]*cv;
            v = v > 0.f ? v : 0.f;
            h1[(wave*16 + quad*4 + r)*136 + col] = f2bf(v);
        }
    }
    __syncthreads();
    floatx4 acc2[8];
    #pragma unroll
    for (int t=0;t<8;t++){
        #pragma unroll
        for(int r=0;r<4;r++) acc2[t][r]=0.f;
    }
    #pragma unroll
    for (int ks=0; ks<4; ks++){
        int koff = ks*32 + quad*8;
        short8 a = *(const short8*)(&h1[(wave*16 + l16)*136 + koff]);
        #pragma unroll
        for (int t=0;t<8;t++){
            short8 b = *(const short8*)(W2t + (size_t)(t*16+l16)*128 + koff);
            acc2[t] = __builtin_amdgcn_mfma_f32_16x16x32_bf16(a,b,acc2[t],0,0,0);
        }
    }
    #pragma unroll
    for (int t=0;t<8;t++){
        int col = t*16+l16;
        float bv = b2[col];
        #pragma unroll
        for (int r=0;r<4;r++){
            out[(size_t)(wrow + quad*4 + r)*128 + col] = acc2[t][r] + bv;
        }
    }
}

// ---- per-graph sum of h_g ----
__global__ __launch_bounds__(128) void k_hgsum(const float* __restrict__ h_g,
                                               float* __restrict__ hgs){
    int g = blockIdx.x, d = threadIdx.x;
    float acc=0;
    const float* p = h_g + (size_t)g*NPG*128 + d;
    for (int n=0;n<NPG;n++) acc += p[(size_t)n*128];
    hgs[g*128+d] = acc;
}

// ---- predictor (fp32) ----
__global__ __launch_bounds__(128) void k_pred(const float* __restrict__ hgs,
        const float* __restrict__ Wp1, const float* __restrict__ bp1,
        const float* __restrict__ Wp2, const float* __restrict__ bp2,
        float* __restrict__ y){
    int g=blockIdx.x, j=threadIdx.x;
    __shared__ float row[128];
    __shared__ float red[128];
    row[j] = hgs[g*128+j];
    __syncthreads();
    float acc = bp1[j];
    for (int k=0;k<128;k++) acc += row[k]*Wp1[k*128+j];
    acc = fmaxf(acc, 0.f);
    red[j] = acc * Wp2[j];
    __syncthreads();
    for (int s=64;s>0;s>>=1){ if (j<s) red[j]+=red[j+s]; __syncthreads(); }
    if (j==0) y[g] = red[0] + bp2[0];
}

extern "C" void kernel_launch(void* const* d_in, const int* in_sizes, int n_in,
                              void* d_out, int out_size, void* d_ws, size_t ws_size,
                              hipStream_t stream) {
    const float* X    = (const float*)d_in[0];
    const float* X_q  = (const float*)d_in[1];
    const int* g_src = (const int*)d_in[2];
    const int* g_dst = (const int*)d_in[3];
    const int* q_src = (const int*)d_in[5];
    const int* q_dst = (const int*)d_in[6];
    const float* Wg   = (const float*)d_in[8];
    const float* bg   = (const float*)d_in[9];
    const float* Wq   = (const float*)d_in[10];
    const float* bq   = (const float*)d_in[11];
    const float* betas_g = (const float*)d_in[12];
    const float* betas_q = (const float*)d_in[13];
    const float* W1r  = (const float*)d_in[14];
    const float* b1r  = (const float*)d_in[15];
    const float* W2r  = (const float*)d_in[16];
    const float* b2r  = (const float*)d_in[17];
    const float* Wp1  = (const float*)d_in[18];
    const float* bp1  = (const float*)d_in[19];
    const float* Wp2  = (const float*)d_in[20];
    const float* bp2  = (const float*)d_in[21];

    uint8_t* w = (uint8_t*)d_ws;
    float* h_g   = (float*)w;                     w += (size_t)NG*128*4;
    float* h_q   = (float*)w;                     w += (size_t)NQ*128*4;
    unsigned short* aout  = (unsigned short*)w;   w += (size_t)NG*128*2;
    float* hqa   = (float*)w;                     w += (size_t)B_*128*4;
    float* Qg    = (float*)w;                     w += (size_t)B_*4*4;
    float* nrm2  = (float*)w;                     w += (size_t)NG*4;
    float* degf  = (float*)w;                     w += (size_t)NG*4;
    float* cg2   = (float*)w;                     w += (size_t)B_*128*4;
    float* hgs   = (float*)w;                     w += (size_t)B_*128*4;
    unsigned short* WgT   = (unsigned short*)w;   w += 8192*2;
    unsigned short* WqT   = (unsigned short*)w;   w += 8192*2;
    unsigned short* W1aT  = (unsigned short*)w;   w += 2*16384*2;
    unsigned short* W2rT  = (unsigned short*)w;   w += 2*16384*2;

    k_transpose<<<320,256,0,stream>>>(Wg,Wq,W1r,W2r,WgT,WqT,W1aT,W2rT);
    k_proj<<<NG/64,256,0,stream>>>(X,   WgT, bg, h_g);
    k_proj<<<NQ/64,256,0,stream>>>(X_q, WqT, bq, h_q);
    for (int l=0;l<L_;l++){
        k_qagnn<<<B_,128,0,stream>>>(h_q, q_src, q_dst, betas_q + l, hqa, Qg);
        k_cvec<<<B_,128,0,stream>>>(hqa, W1r + l*32768, cg2);
        k_norm<<<NG/4,256,0,stream>>>(h_g, nrm2);
        k_gagnn<<<B_,256,0,stream>>>(h_g, nrm2, Qg, g_src, g_dst, betas_g + l, aout, degf);
        k_mlp<<<NG/64,256,0,stream>>>(aout, W1aT + l*16384, b1r + l*128, cg2, degf,
                                      W2rT + l*16384, b2r + l*128, h_g);
    }
    k_hgsum<<<B_,128,0,stream>>>(h_g, hgs);
    k_pred<<<B_,128,0,stream>>>(hgs, Wp1, bp1, Wp2, bp2, (float*)d_out);
}

// Round 5
// 741.793 us; speedup vs baseline: 2.6161x; 2.6161x over previous
//
#include <hip/hip_runtime.h>
#include <stdint.h>

#define B_   256
#define NPG  512
#define NG   131072
#define EPG  4096
#define NQPG 16
#define NQ   4096
#define EQPG 128
#define L_   2

typedef __attribute__((ext_vector_type(8))) short short8;
typedef __attribute__((ext_vector_type(4))) float floatx4;

__device__ inline float bf2f(unsigned short u){
    union { unsigned int i; float f; } x; x.i = ((unsigned int)u) << 16; return x.f;
}
__device__ inline unsigned short f2bf(float f){
    union { float f; unsigned int i; } x; x.f = f;
    unsigned int r = x.i + 0x7fff + ((x.i >> 16) & 1);  // RNE
    return (unsigned short)(r >> 16);
}

// ---- transpose weights (fp32 in) to [N][K] bf16 ----
__global__ void k_transpose(const float* Wg, const float* Wq,
                            const float* W1r, const float* W2r,
                            unsigned short* WgT, unsigned short* WqT,
                            unsigned short* W1aT, unsigned short* W2rT){
    int idx = blockIdx.x*256 + threadIdx.x;
    if (idx < 8192){                       // Wg [64,128] -> WgT [128][64]
        int k = idx >> 7, n = idx & 127; WgT[n*64 + k] = f2bf(Wg[idx]);
    } else if (idx < 16384){
        int i = idx - 8192; int k = i>>7, n = i&127; WqT[n*64+k] = f2bf(Wq[i]);
    } else if (idx < 49152){               // W1r[l][0:128,:] -> W1aT[l][128][128]
        int i = idx - 16384; int l = i >> 14; int j = i & 16383; int k = j>>7, n = j&127;
        W1aT[l*16384 + n*128 + k] = f2bf(W1r[l*32768 + j]);
    } else {                               // W2r[l] [128,128] -> W2rT[l][128][128]
        int i = idx - 49152; int l = i >> 14; int j = i & 16383; int k = j>>7, n = j&127;
        W2rT[l*16384 + n*128 + k] = f2bf(W2r[i]);
    }
}

// ---- proj: out_bf16[M,128] = A_f32[M,64] @ WtT + bias ; optional row sumsq ----
__global__ __launch_bounds__(256) void k_proj(const float* __restrict__ A,
        const unsigned short* __restrict__ Wt, const float* __restrict__ bias,
        unsigned short* __restrict__ out, float* __restrict__ nrm2){
    const int K = 64;
    int wave = threadIdx.x >> 6, lane = threadIdx.x & 63;
    int quad = lane >> 4, l16 = lane & 15;
    int wrow = blockIdx.x*64 + wave*16;
    floatx4 acc[8];
    #pragma unroll
    for (int t=0;t<8;t++){
        #pragma unroll
        for (int r=0;r<4;r++) acc[t][r]=0.f;
    }
    #pragma unroll
    for (int ks = 0; ks < 2; ks++){
        int koff = ks*32 + quad*8;
        const float* ap = A + (size_t)(wrow+l16)*K + koff;
        short8 a;
        #pragma unroll
        for (int j=0;j<8;j++) a[j] = (short)f2bf(ap[j]);
        #pragma unroll
        for (int t=0;t<8;t++){
            short8 b = *(const short8*)(Wt + (size_t)(t*16+l16)*K + koff);
            acc[t] = __builtin_amdgcn_mfma_f32_16x16x32_bf16(a, b, acc[t], 0,0,0);
        }
    }
    float ss[4] = {0.f,0.f,0.f,0.f};
    #pragma unroll
    for (int t=0;t<8;t++){
        int col = t*16 + l16;
        float bv = bias[col];
        #pragma unroll
        for (int r=0;r<4;r++){
            float v = acc[t][r] + bv;
            out[(size_t)(wrow + quad*4 + r)*128 + col] = f2bf(v);
            ss[r] += v*v;
        }
    }
    if (nrm2){
        #pragma unroll
        for (int r=0;r<4;r++){
            #pragma unroll
            for (int o=1;o<16;o<<=1) ss[r] += __shfl_xor(ss[r], o);
        }
        if (l16==0){
            #pragma unroll
            for (int r=0;r<4;r++) nrm2[wrow + quad*4 + r] = ss[r];
        }
    }
}

// ---- query AGNN (bf16 h_q) + per-graph sum + Qg = ||hqa||^2 ----
__global__ __launch_bounds__(128) void k_qagnn(unsigned short* __restrict__ h_q,
        const int* __restrict__ q_src, const int* __restrict__ q_dst,
        const float* __restrict__ beta_p, float* __restrict__ hqa,
        float* __restrict__ Qg){
    int g = blockIdx.x, t = threadIdx.x;
    __shared__ float h[NQPG][132];
    __shared__ float e[EQPG], w[EQPG];
    __shared__ float inv[NQPG], mx[NQPG], den[NQPG];
    __shared__ int srcl[EQPG], dstl[EQPG], csr[EQPG];
    __shared__ int cnt[NQPG], off[NQPG], woff[NQPG];
    __shared__ float part[128];
    float beta = beta_p[0];
    for (int idx=t; idx<NQPG*128; idx+=128){
        int n = idx>>7, d = idx&127;
        h[n][d] = bf2f(h_q[(size_t)(g*NQPG+n)*128 + d]);
    }
    if (t<NQPG){ cnt[t]=0; mx[t]=0.f; den[t]=0.f; }
    __syncthreads();
    { int n=t>>3, c=t&7; float s=0;
      for (int d=c*16; d<c*16+16; d++){ float v=h[n][d]; s+=v*v; }
      part[t]=s; }
    __syncthreads();
    if (t<NQPG){ float s=0; for(int c=0;c<8;c++) s+=part[t*8+c]; inv[t]=rsqrtf(s+1e-24f); }
    __syncthreads();
    { int eidx = g*EQPG + t;
      int s = q_src[eidx] - g*NQPG, d = q_dst[eidx] - g*NQPG;
      srcl[t]=s; dstl[t]=d;
      float dot=0;
      for (int k=0;k<128;k++) dot += h[s][k]*h[d][k];
      e[t] = beta*dot*inv[s]*inv[d];
      atomicAdd(&cnt[d],1); }
    __syncthreads();
    if (t==0){ int o=0; for(int i=0;i<NQPG;i++){ off[i]=o; o+=cnt[i]; } }
    __syncthreads();
    if (t<NQPG){ woff[t]=off[t];
        if (cnt[t] > 0){
            float mm=-1e30f, dd=0.f;
            for (int j=0;j<EQPG;j++) if (dstl[j]==t) mm = fmaxf(mm, e[j]);
            for (int j=0;j<EQPG;j++) if (dstl[j]==t) dd += __expf(e[j]-mm);
            mx[t]=mm; den[t]=dd;
        } }
    __syncthreads();
    { int d = dstl[t];
      float dd = den[d];
      w[t] = dd > 0.f ? __expf(e[t]-mx[d]) / dd : 0.f;
      int pos = atomicAdd(&woff[d],1);
      csr[pos]=t; }
    __syncthreads();
    float aggr=0.f;
    { int d = t;
      for (int n=0;n<NQPG;n++){
          float acc=0.f;
          int o=off[n], c=cnt[n];
          for (int j=o;j<o+c;j++){ int ei=csr[j]; acc += w[ei]*h[srcl[ei]][d]; }
          h_q[(size_t)(g*NQPG+n)*128 + d] = f2bf(acc);
          aggr += acc;
      }
      hqa[g*128+d]=aggr; }
    __syncthreads();
    part[t] = aggr*aggr;
    __syncthreads();
    for (int s2=64; s2>0; s2>>=1){
        if (t<s2) part[t]+=part[t+s2];
        __syncthreads();
    }
    if (t==0) Qg[g]=part[0];
}

// ---- per-graph cg2 = hqa @ W1r[l][128:256,:] (fp32) ----
__global__ __launch_bounds__(128) void k_cvec(const float* __restrict__ hqa,
        const float* __restrict__ W1r_l, float* __restrict__ cg2){
    int g = blockIdx.x, j = threadIdx.x;
    __shared__ float hq[128];
    hq[j] = hqa[g*128+j];
    __syncthreads();
    float acc = 0.f;
    for (int k=0;k<128;k++) acc += hq[k]*W1r_l[(128+k)*128 + j];
    cg2[g*128+j] = acc;
}

// ---- data-graph AGNN; h_g bf16, raw-row gather, inv folded into logit scalar ----
__global__ __launch_bounds__(1024) void k_gagnn(const unsigned short* __restrict__ h_g,
        const float* __restrict__ nrm2, const float* __restrict__ Qg,
        const int* __restrict__ g_src, const int* __restrict__ g_dst,
        const float* __restrict__ beta_p,
        unsigned short* __restrict__ aout, float* __restrict__ degf){
    int g = blockIdx.x, t = threadIdx.x;
    int wave = t>>6, lane = t&63;
    __shared__ unsigned short srcl[EPG], dstl[EPG], csr[EPG];
    __shared__ float e[EPG];
    __shared__ float inv[NPG], mx[NPG], den[NPG];
    __shared__ int cnt[NPG], off[NPG], woff[NPG];
    __shared__ int gscan[64];
    float beta = beta_p[0];
    float Q = Qg[g];
    int gbase = g*NPG;
    for (int i=t; i<NPG; i+=1024){
        inv[i] = rsqrtf(nrm2[gbase+i] + Q + 1e-24f);
        cnt[i]=0; mx[i]=0.f; den[i]=0.f;
    }
    __syncthreads();
    for (int i=t; i<EPG; i+=1024){
        int s = g_src[(size_t)g*EPG+i] - gbase;
        int d = g_dst[(size_t)g*EPG+i] - gbase;
        srcl[i] = (unsigned short)s;
        dstl[i] = (unsigned short)d;
        atomicAdd(&cnt[d], 1);
    }
    __syncthreads();
    // edge logits: wave per edge; lane covers 2 dims (bf16x2 = 4B/lane, 256B/row coalesced)
    for (int ei = wave; ei < EPG; ei += 16){
        int s = srcl[ei], d = dstl[ei];
        unsigned int us = *(const unsigned int*)(h_g + (size_t)(gbase+s)*128 + lane*2);
        unsigned int ud = *(const unsigned int*)(h_g + (size_t)(gbase+d)*128 + lane*2);
        float v = bf2f((unsigned short)(us&0xffff))*bf2f((unsigned short)(ud&0xffff))
                + bf2f((unsigned short)(us>>16))  *bf2f((unsigned short)(ud>>16));
        #pragma unroll
        for (int o=32;o>0;o>>=1) v += __shfl_xor(v,o);
        if (lane==0) e[ei] = beta * (v + Q) * inv[s]*inv[d];
    }
    __syncthreads();
    // hierarchical exclusive scan of cnt -> off
    if (t < 64){
        int s = 0;
        #pragma unroll
        for (int j=0;j<8;j++) s += cnt[t*8+j];
        int v = s;
        #pragma unroll
        for (int o=1;o<64;o<<=1){
            int u = __shfl_up(v,o);
            if (lane >= o) v += u;
        }
        gscan[t] = v;   // inclusive over 8-groups
    }
    __syncthreads();
    if (t < NPG){
        int grp = t>>3;
        int base = grp ? gscan[grp-1] : 0;
        for (int j=grp*8; j<t; j++) base += cnt[j];
        off[t] = base; woff[t] = base;
    }
    __syncthreads();
    for (int i=t;i<EPG;i+=1024){
        int pos = atomicAdd(&woff[dstl[i]],1);
        csr[pos] = (unsigned short)i;
    }
    __syncthreads();
    for (int n=t;n<NPG;n+=1024){
        int c=cnt[n];
        if (c > 0){
            int o=off[n];
            float mm=-1e30f;
            for (int j=0;j<c;j++) mm = fmaxf(mm, e[csr[o+j]]);
            float dd=0.f;
            for (int j=0;j<c;j++) dd += __expf(e[csr[o+j]]-mm);
            mx[n]=mm; den[n]=dd;
        }
    }
    __syncthreads();
    for (int i=t;i<EPG;i+=1024){
        int d = dstl[i];
        float dd = den[d];
        e[i] = dd > 0.f ? __expf(e[i]-mx[d]) / dd : 0.f;
    }
    __syncthreads();
    // weighted gather of raw bf16 rows, wave per node
    for (int n=wave; n<NPG; n+=16){
        int c = cnt[n], o = off[n];
        float a0=0.f, a1=0.f;
        for (int j=0;j<c;j++){
            int ei = csr[o+j];
            int s = srcl[ei];
            float wg = e[ei];
            unsigned int us = *(const unsigned int*)(h_g + (size_t)(gbase+s)*128 + lane*2);
            a0 += wg*bf2f((unsigned short)(us&0xffff));
            a1 += wg*bf2f((unsigned short)(us>>16));
        }
        unsigned int ov = (unsigned int)f2bf(a0) | ((unsigned int)f2bf(a1)<<16);
        *(unsigned int*)(aout + (size_t)(gbase+n)*128 + lane*2) = ov;
        if (lane==0) degf[gbase+n] = (c>0) ? 1.f : 0.f;
    }
}

// ---- fused MLP: h_g = relu(A@W1a + b1 + deg*cg2)@W2 + b2 ; bf16 out + nrm2 ----
__global__ __launch_bounds__(256) void k_mlp(const unsigned short* __restrict__ A,
        const unsigned short* __restrict__ W1t, const float* __restrict__ b1,
        const float* __restrict__ cg2, const float* __restrict__ degf,
        const unsigned short* __restrict__ W2t, const float* __restrict__ b2,
        unsigned short* __restrict__ out, float* __restrict__ nrm2){
    __shared__ __align__(16) unsigned short h1[64*136];
    int wave = threadIdx.x>>6, lane = threadIdx.x&63;
    int quad = lane>>4, l16 = lane&15;
    int wrow = blockIdx.x*64 + wave*16;
    const float* cg = cg2 + (size_t)(blockIdx.x>>3)*128;
    floatx4 acc[8];
    #pragma unroll
    for (int t=0;t<8;t++){
        #pragma unroll
        for(int r=0;r<4;r++) acc[t][r]=0.f;
    }
    #pragma unroll
    for (int ks=0; ks<4; ks++){
        int koff = ks*32 + quad*8;
        short8 a = *(const short8*)(A + (size_t)(wrow+l16)*128 + koff);
        #pragma unroll
        for (int t=0;t<8;t++){
            short8 b = *(const short8*)(W1t + (size_t)(t*16+l16)*128 + koff);
            acc[t] = __builtin_amdgcn_mfma_f32_16x16x32_bf16(a,b,acc[t],0,0,0);
        }
    }
    float dg[4];
    #pragma unroll
    for (int r=0;r<4;r++) dg[r] = degf[wrow + quad*4 + r];
    #pragma unroll
    for (int t=0;t<8;t++){
        int col = t*16+l16;
        float bv = b1[col];
        float cv = cg[col];
        #pragma unroll
        for (int r=0;r<4;r++){
            float v = acc[t][r] + bv + dg[r]*cv;
            v = v > 0.f ? v : 0.f;
            h1[(wave*16 + quad*4 + r)*136 + col] = f2bf(v);
        }
    }
    __syncthreads();
    floatx4 acc2[8];
    #pragma unroll
    for (int t=0;t<8;t++){
        #pragma unroll
        for(int r=0;r<4;r++) acc2[t][r]=0.f;
    }
    #pragma unroll
    for (int ks=0; ks<4; ks++){
        int koff = ks*32 + quad*8;
        short8 a = *(const short8*)(&h1[(wave*16 + l16)*136 + koff]);
        #pragma unroll
        for (int t=0;t<8;t++){
            short8 b = *(const short8*)(W2t + (size_t)(t*16+l16)*128 + koff);
            acc2[t] = __builtin_amdgcn_mfma_f32_16x16x32_bf16(a,b,acc2[t],0,0,0);
        }
    }
    float ss[4] = {0.f,0.f,0.f,0.f};
    #pragma unroll
    for (int t=0;t<8;t++){
        int col = t*16+l16;
        float bv = b2[col];
        #pragma unroll
        for (int r=0;r<4;r++){
            float v = acc2[t][r] + bv;
            out[(size_t)(wrow + quad*4 + r)*128 + col] = f2bf(v);
            ss[r] += v*v;
        }
    }
    #pragma unroll
    for (int r=0;r<4;r++){
        #pragma unroll
        for (int o=1;o<16;o<<=1) ss[r] += __shfl_xor(ss[r], o);
    }
    if (l16==0){
        #pragma unroll
        for (int r=0;r<4;r++) nrm2[wrow + quad*4 + r] = ss[r];
    }
}

// ---- per-graph sum of h_g (bf16) ----
__global__ __launch_bounds__(128) void k_hgsum(const unsigned short* __restrict__ h_g,
                                               float* __restrict__ hgs){
    int g = blockIdx.x, d = threadIdx.x;
    float acc=0;
    const unsigned short* p = h_g + (size_t)g*NPG*128 + d;
    for (int n=0;n<NPG;n++) acc += bf2f(p[(size_t)n*128]);
    hgs[g*128+d] = acc;
}

// ---- predictor (fp32) ----
__global__ __launch_bounds__(128) void k_pred(const float* __restrict__ hgs,
        const float* __restrict__ Wp1, const float* __restrict__ bp1,
        const float* __restrict__ Wp2, const float* __restrict__ bp2,
        float* __restrict__ y){
    int g=blockIdx.x, j=threadIdx.x;
    __shared__ float row[128];
    __shared__ float red[128];
    row[j] = hgs[g*128+j];
    __syncthreads();
    float acc = bp1[j];
    for (int k=0;k<128;k++) acc += row[k]*Wp1[k*128+j];
    acc = fmaxf(acc, 0.f);
    red[j] = acc * Wp2[j];
    __syncthreads();
    for (int s=64;s>0;s>>=1){ if (j<s) red[j]+=red[j+s]; __syncthreads(); }
    if (j==0) y[g] = red[0] + bp2[0];
}

extern "C" void kernel_launch(void* const* d_in, const int* in_sizes, int n_in,
                              void* d_out, int out_size, void* d_ws, size_t ws_size,
                              hipStream_t stream) {
    const float* X    = (const float*)d_in[0];
    const float* X_q  = (const float*)d_in[1];
    const int* g_src = (const int*)d_in[2];
    const int* g_dst = (const int*)d_in[3];
    const int* q_src = (const int*)d_in[5];
    const int* q_dst = (const int*)d_in[6];
    const float* Wg   = (const float*)d_in[8];
    const float* bg   = (const float*)d_in[9];
    const float* Wq   = (const float*)d_in[10];
    const float* bq   = (const float*)d_in[11];
    const float* betas_g = (const float*)d_in[12];
    const float* betas_q = (const float*)d_in[13];
    const float* W1r  = (const float*)d_in[14];
    const float* b1r  = (const float*)d_in[15];
    const float* W2r  = (const float*)d_in[16];
    const float* b2r  = (const float*)d_in[17];
    const float* Wp1  = (const float*)d_in[18];
    const float* bp1  = (const float*)d_in[19];
    const float* Wp2  = (const float*)d_in[20];
    const float* bp2  = (const float*)d_in[21];

    uint8_t* w = (uint8_t*)d_ws;
    unsigned short* h_g  = (unsigned short*)w;    w += (size_t)NG*128*2;
    unsigned short* h_q  = (unsigned short*)w;    w += (size_t)NQ*128*2;
    unsigned short* aout = (unsigned short*)w;    w += (size_t)NG*128*2;
    float* nrm2  = (float*)w;                     w += (size_t)NG*4;
    float* degf  = (float*)w;                     w += (size_t)NG*4;
    float* hqa   = (float*)w;                     w += (size_t)B_*128*4;
    float* Qg    = (float*)w;                     w += (size_t)B_*4*4;
    float* cg2   = (float*)w;                     w += (size_t)B_*128*4;
    float* hgs   = (float*)w;                     w += (size_t)B_*128*4;
    unsigned short* WgT   = (unsigned short*)w;   w += 8192*2;
    unsigned short* WqT   = (unsigned short*)w;   w += 8192*2;
    unsigned short* W1aT  = (unsigned short*)w;   w += 2*16384*2;
    unsigned short* W2rT  = (unsigned short*)w;   w += 2*16384*2;

    k_transpose<<<320,256,0,stream>>>(Wg,Wq,W1r,W2r,WgT,WqT,W1aT,W2rT);
    k_proj<<<NG/64,256,0,stream>>>(X,   WgT, bg, h_g, nrm2);
    k_proj<<<NQ/64,256,0,stream>>>(X_q, WqT, bq, h_q, nullptr);
    for (int l=0;l<L_;l++){
        k_qagnn<<<B_,128,0,stream>>>(h_q, q_src, q_dst, betas_q + l, hqa, Qg);
        k_cvec<<<B_,128,0,stream>>>(hqa, W1r + l*32768, cg2);
        k_gagnn<<<B_,1024,0,stream>>>(h_g, nrm2, Qg, g_src, g_dst, betas_g + l, aout, degf);
        k_mlp<<<NG/64,256,0,stream>>>(aout, W1aT + l*16384, b1r + l*128, cg2, degf,
                                      W2rT + l*16384, b2r + l*128, h_g, nrm2);
    }
    k_hgsum<<<B_,128,0,stream>>>(h_g, hgs);
    k_pred<<<B_,128,0,stream>>>(hgs, Wp1, bp1, Wp2, bp2, (float*)d_out);
}

// Round 6
// 522.234 us; speedup vs baseline: 3.7159x; 1.4204x over previous
//
#include <hip/hip_runtime.h>
#include <stdint.h>

#define B_   256
#define NPG  512
#define NG   131072
#define EPG  4096
#define NQPG 16
#define NQ   4096
#define EQPG 128
#define L_   2

typedef __attribute__((ext_vector_type(8))) short short8;
typedef __attribute__((ext_vector_type(4))) float floatx4;

__device__ inline float bf2f(unsigned short u){
    union { unsigned int i; float f; } x; x.i = ((unsigned int)u) << 16; return x.f;
}
__device__ inline unsigned short f2bf(float f){
    union { float f; unsigned int i; } x; x.f = f;
    unsigned int r = x.i + 0x7fff + ((x.i >> 16) & 1);  // RNE
    return (unsigned short)(r >> 16);
}
__device__ inline float dot8(uint4 a, uint4 b){
    float v;
    v  = bf2f((unsigned short)(a.x&0xffff))*bf2f((unsigned short)(b.x&0xffff));
    v  = fmaf(bf2f((unsigned short)(a.x>>16)),  bf2f((unsigned short)(b.x>>16)), v);
    v  = fmaf(bf2f((unsigned short)(a.y&0xffff)),bf2f((unsigned short)(b.y&0xffff)), v);
    v  = fmaf(bf2f((unsigned short)(a.y>>16)),  bf2f((unsigned short)(b.y>>16)), v);
    v  = fmaf(bf2f((unsigned short)(a.z&0xffff)),bf2f((unsigned short)(b.z&0xffff)), v);
    v  = fmaf(bf2f((unsigned short)(a.z>>16)),  bf2f((unsigned short)(b.z>>16)), v);
    v  = fmaf(bf2f((unsigned short)(a.w&0xffff)),bf2f((unsigned short)(b.w&0xffff)), v);
    v  = fmaf(bf2f((unsigned short)(a.w>>16)),  bf2f((unsigned short)(b.w>>16)), v);
    return v;
}

// ---- transpose weights (fp32 in) to [N][K] bf16 ----
__global__ void k_transpose(const float* Wg, const float* Wq,
                            const float* W1r, const float* W2r,
                            unsigned short* WgT, unsigned short* WqT,
                            unsigned short* W1aT, unsigned short* W2rT){
    int idx = blockIdx.x*256 + threadIdx.x;
    if (idx < 8192){
        int k = idx >> 7, n = idx & 127; WgT[n*64 + k] = f2bf(Wg[idx]);
    } else if (idx < 16384){
        int i = idx - 8192; int k = i>>7, n = i&127; WqT[n*64+k] = f2bf(Wq[i]);
    } else if (idx < 49152){
        int i = idx - 16384; int l = i >> 14; int j = i & 16383; int k = j>>7, n = j&127;
        W1aT[l*16384 + n*128 + k] = f2bf(W1r[l*32768 + j]);
    } else {
        int i = idx - 49152; int l = i >> 14; int j = i & 16383; int k = j>>7, n = j&127;
        W2rT[l*16384 + n*128 + k] = f2bf(W2r[i]);
    }
}

// ---- one-shot CSR build per data graph (topology is layer-invariant) ----
__global__ __launch_bounds__(256) void k_csr(const int* __restrict__ g_src,
        const int* __restrict__ g_dst,
        unsigned short* __restrict__ srcl_g, unsigned short* __restrict__ dstl_g,
        unsigned short* __restrict__ csr_g, int* __restrict__ off_g,
        int* __restrict__ cnt_g, float* __restrict__ degf){
    int g = blockIdx.x, t = threadIdx.x, lane = t & 63;
    __shared__ int cnt[NPG], off[NPG], woff[NPG];
    __shared__ int gscan[64];
    int gbase = g*NPG; size_t ebase = (size_t)g*EPG;
    for (int n=t;n<NPG;n+=256) cnt[n]=0;
    __syncthreads();
    for (int i=t;i<EPG;i+=256){
        int s = g_src[ebase+i]-gbase, d = g_dst[ebase+i]-gbase;
        srcl_g[ebase+i]=(unsigned short)s; dstl_g[ebase+i]=(unsigned short)d;
        atomicAdd(&cnt[d],1);
    }
    __syncthreads();
    if (t < 64){
        int s=0;
        #pragma unroll
        for (int j=0;j<8;j++) s += cnt[t*8+j];
        int v=s;
        #pragma unroll
        for (int o=1;o<64;o<<=1){ int u=__shfl_up(v,o); if (lane>=o) v+=u; }
        gscan[t]=v;
    }
    __syncthreads();
    for (int n=t;n<NPG;n+=256){
        int grp=n>>3; int base = grp?gscan[grp-1]:0;
        for (int j=grp*8;j<n;j++) base+=cnt[j];
        off[n]=base; woff[n]=base;
    }
    __syncthreads();
    for (int i=t;i<EPG;i+=256){
        int d = g_dst[ebase+i]-gbase;
        int pos = atomicAdd(&woff[d],1);
        csr_g[ebase+pos]=(unsigned short)i;
    }
    __syncthreads();
    for (int n=t;n<NPG;n+=256){
        off_g[g*NPG+n]=off[n]; cnt_g[g*NPG+n]=cnt[n];
        degf[gbase+n] = cnt[n]>0 ? 1.f : 0.f;
    }
}

// ---- proj: out_bf16[M,128] = A_f32[M,64] @ WtT + bias ; optional row sumsq ----
__global__ __launch_bounds__(256) void k_proj(const float* __restrict__ A,
        const unsigned short* __restrict__ Wt, const float* __restrict__ bias,
        unsigned short* __restrict__ out, float* __restrict__ nrm2){
    const int K = 64;
    int wave = threadIdx.x >> 6, lane = threadIdx.x & 63;
    int quad = lane >> 4, l16 = lane & 15;
    int wrow = blockIdx.x*64 + wave*16;
    floatx4 acc[8];
    #pragma unroll
    for (int t=0;t<8;t++){
        #pragma unroll
        for (int r=0;r<4;r++) acc[t][r]=0.f;
    }
    #pragma unroll
    for (int ks = 0; ks < 2; ks++){
        int koff = ks*32 + quad*8;
        const float* ap = A + (size_t)(wrow+l16)*K + koff;
        short8 a;
        #pragma unroll
        for (int j=0;j<8;j++) a[j] = (short)f2bf(ap[j]);
        #pragma unroll
        for (int t=0;t<8;t++){
            short8 b = *(const short8*)(Wt + (size_t)(t*16+l16)*K + koff);
            acc[t] = __builtin_amdgcn_mfma_f32_16x16x32_bf16(a, b, acc[t], 0,0,0);
        }
    }
    float ss[4] = {0.f,0.f,0.f,0.f};
    #pragma unroll
    for (int t=0;t<8;t++){
        int col = t*16 + l16;
        float bv = bias[col];
        #pragma unroll
        for (int r=0;r<4;r++){
            float v = acc[t][r] + bv;
            out[(size_t)(wrow + quad*4 + r)*128 + col] = f2bf(v);
            ss[r] += v*v;
        }
    }
    if (nrm2){
        #pragma unroll
        for (int r=0;r<4;r++){
            #pragma unroll
            for (int o=1;o<16;o<<=1) ss[r] += __shfl_xor(ss[r], o);
        }
        if (l16==0){
            #pragma unroll
            for (int r=0;r<4;r++) nrm2[wrow + quad*4 + r] = ss[r];
        }
    }
}

// ---- query AGNN (bf16 h_q) + per-graph sum + Qg = ||hqa||^2 ----
__global__ __launch_bounds__(128) void k_qagnn(unsigned short* __restrict__ h_q,
        const int* __restrict__ q_src, const int* __restrict__ q_dst,
        const float* __restrict__ beta_p, float* __restrict__ hqa,
        float* __restrict__ Qg){
    int g = blockIdx.x, t = threadIdx.x;
    __shared__ float h[NQPG][132];
    __shared__ float e[EQPG], w[EQPG];
    __shared__ float inv[NQPG], mx[NQPG], den[NQPG];
    __shared__ int srcl[EQPG], dstl[EQPG], csr[EQPG];
    __shared__ int cnt[NQPG], off[NQPG], woff[NQPG];
    __shared__ float part[128];
    float beta = beta_p[0];
    for (int idx=t; idx<NQPG*128; idx+=128){
        int n = idx>>7, d = idx&127;
        h[n][d] = bf2f(h_q[(size_t)(g*NQPG+n)*128 + d]);
    }
    if (t<NQPG){ cnt[t]=0; mx[t]=0.f; den[t]=0.f; }
    __syncthreads();
    { int n=t>>3, c=t&7; float s=0;
      for (int d=c*16; d<c*16+16; d++){ float v=h[n][d]; s+=v*v; }
      part[t]=s; }
    __syncthreads();
    if (t<NQPG){ float s=0; for(int c=0;c<8;c++) s+=part[t*8+c]; inv[t]=rsqrtf(s+1e-24f); }
    __syncthreads();
    { int eidx = g*EQPG + t;
      int s = q_src[eidx] - g*NQPG, d = q_dst[eidx] - g*NQPG;
      srcl[t]=s; dstl[t]=d;
      float dot=0;
      for (int k=0;k<128;k++) dot += h[s][k]*h[d][k];
      e[t] = beta*dot*inv[s]*inv[d];
      atomicAdd(&cnt[d],1); }
    __syncthreads();
    if (t==0){ int o=0; for(int i=0;i<NQPG;i++){ off[i]=o; o+=cnt[i]; } }
    __syncthreads();
    if (t<NQPG){ woff[t]=off[t];
        if (cnt[t] > 0){
            float mm=-1e30f, dd=0.f;
            for (int j=0;j<EQPG;j++) if (dstl[j]==t) mm = fmaxf(mm, e[j]);
            for (int j=0;j<EQPG;j++) if (dstl[j]==t) dd += __expf(e[j]-mm);
            mx[t]=mm; den[t]=dd;
        } }
    __syncthreads();
    { int d = dstl[t];
      float dd = den[d];
      w[t] = dd > 0.f ? __expf(e[t]-mx[d]) / dd : 0.f;
      int pos = atomicAdd(&woff[d],1);
      csr[pos]=t; }
    __syncthreads();
    float aggr=0.f;
    { int d = t;
      for (int n=0;n<NQPG;n++){
          float acc=0.f;
          int o=off[n], c=cnt[n];
          for (int j=o;j<o+c;j++){ int ei=csr[j]; acc += w[ei]*h[srcl[ei]][d]; }
          h_q[(size_t)(g*NQPG+n)*128 + d] = f2bf(acc);
          aggr += acc;
      }
      hqa[g*128+d]=aggr; }
    __syncthreads();
    part[t] = aggr*aggr;
    __syncthreads();
    for (int s2=64; s2>0; s2>>=1){
        if (t<s2) part[t]+=part[t+s2];
        __syncthreads();
    }
    if (t==0) Qg[g]=part[0];
}

// ---- per-graph cg2 = hqa @ W1r[l][128:256,:] (fp32) ----
__global__ __launch_bounds__(128) void k_cvec(const float* __restrict__ hqa,
        const float* __restrict__ W1r_l, float* __restrict__ cg2){
    int g = blockIdx.x, j = threadIdx.x;
    __shared__ float hq[128];
    hq[j] = hqa[g*128+j];
    __syncthreads();
    float acc = 0.f;
    for (int k=0;k<128;k++) acc += hq[k]*W1r_l[(128+k)*128 + j];
    cg2[g*128+j] = acc;
}

// ---- data-graph AGNN; precomputed CSR, 16-lane subwave edges/nodes ----
__global__ __launch_bounds__(1024) void k_gagnn(const unsigned short* __restrict__ h_g,
        const float* __restrict__ nrm2, const float* __restrict__ Qg,
        const unsigned short* __restrict__ srcl_g, const unsigned short* __restrict__ dstl_g,
        const unsigned short* __restrict__ csr_g, const int* __restrict__ off_g,
        const int* __restrict__ cnt_g, const float* __restrict__ beta_p,
        unsigned short* __restrict__ aout){
    int g = blockIdx.x, t = threadIdx.x;
    int wave = t>>6, lane = t&63, sub = lane>>4, sl = lane&15;
    __shared__ float e[EPG];
    __shared__ unsigned short srcl[EPG], dstl[EPG], csr[EPG];
    __shared__ float inv[NPG], mx[NPG], den[NPG];
    __shared__ int off[NPG];
    __shared__ unsigned short cnts[NPG];
    float beta = beta_p[0];
    float Q = Qg[g];
    int gbase = g*NPG;
    size_t ebase = (size_t)g*EPG;
    for (int i=t; i<EPG; i+=1024){
        srcl[i] = srcl_g[ebase+i];
        dstl[i] = dstl_g[ebase+i];
        csr[i]  = csr_g[ebase+i];
    }
    for (int n=t; n<NPG; n+=1024){
        inv[n] = rsqrtf(nrm2[gbase+n] + Q + 1e-24f);
        off[n] = off_g[g*NPG+n];
        cnts[n] = (unsigned short)cnt_g[g*NPG+n];
    }
    __syncthreads();
    // edge logits: 16 lanes per edge (16B/lane dwordx4), 4 edges/wave concurrently
    for (int ei = wave*4 + sub; ei < EPG; ei += 64){
        int s = srcl[ei], d = dstl[ei];
        uint4 us = *(const uint4*)(h_g + (size_t)(gbase+s)*128 + sl*8);
        uint4 ud = *(const uint4*)(h_g + (size_t)(gbase+d)*128 + sl*8);
        float v = dot8(us, ud);
        v += __shfl_xor(v,1); v += __shfl_xor(v,2);
        v += __shfl_xor(v,4); v += __shfl_xor(v,8);
        if (sl==0) e[ei] = beta * (v + Q) * inv[s]*inv[d];
    }
    __syncthreads();
    // per-node max/den (every edge's dst has cnt>=1, so mx/den for used nodes always set)
    for (int n=t; n<NPG; n+=1024){
        int c = cnts[n];
        if (c > 0){
            int o = off[n];
            float mm = -1e30f;
            for (int j=0;j<c;j++) mm = fmaxf(mm, e[csr[o+j]]);
            float dd = 0.f;
            for (int j=0;j<c;j++) dd += __expf(e[csr[o+j]]-mm);
            mx[n]=mm; den[n]=dd;
        }
    }
    __syncthreads();
    for (int i=t; i<EPG; i+=1024){
        int d = dstl[i];
        e[i] = __expf(e[i]-mx[d]) / den[d];
    }
    __syncthreads();
    // weighted gather: 16 lanes per node, 4 nodes/wave concurrently
    for (int n = wave*4 + sub; n < NPG; n += 64){
        int c = cnts[n], o = off[n];
        float a0=0,a1=0,a2=0,a3=0,a4=0,a5=0,a6=0,a7=0;
        for (int j=0;j<c;j++){
            int ei = csr[o+j];
            float wg = e[ei];
            int s = srcl[ei];
            uint4 us = *(const uint4*)(h_g + (size_t)(gbase+s)*128 + sl*8);
            a0 = fmaf(wg, bf2f((unsigned short)(us.x&0xffff)), a0);
            a1 = fmaf(wg, bf2f((unsigned short)(us.x>>16)),   a1);
            a2 = fmaf(wg, bf2f((unsigned short)(us.y&0xffff)), a2);
            a3 = fmaf(wg, bf2f((unsigned short)(us.y>>16)),   a3);
            a4 = fmaf(wg, bf2f((unsigned short)(us.z&0xffff)), a4);
            a5 = fmaf(wg, bf2f((unsigned short)(us.z>>16)),   a5);
            a6 = fmaf(wg, bf2f((unsigned short)(us.w&0xffff)), a6);
            a7 = fmaf(wg, bf2f((unsigned short)(us.w>>16)),   a7);
        }
        uint4 ov;
        ov.x = (unsigned int)f2bf(a0) | ((unsigned int)f2bf(a1)<<16);
        ov.y = (unsigned int)f2bf(a2) | ((unsigned int)f2bf(a3)<<16);
        ov.z = (unsigned int)f2bf(a4) | ((unsigned int)f2bf(a5)<<16);
        ov.w = (unsigned int)f2bf(a6) | ((unsigned int)f2bf(a7)<<16);
        *(uint4*)(aout + (size_t)(gbase+n)*128 + sl*8) = ov;
    }
}

// ---- fused MLP: h_g = relu(A@W1a + b1 + deg*cg2)@W2 + b2 ; bf16 out + nrm2 ----
__global__ __launch_bounds__(256) void k_mlp(const unsigned short* __restrict__ A,
        const unsigned short* __restrict__ W1t, const float* __restrict__ b1,
        const float* __restrict__ cg2, const float* __restrict__ degf,
        const unsigned short* __restrict__ W2t, const float* __restrict__ b2,
        unsigned short* __restrict__ out, float* __restrict__ nrm2){
    __shared__ __align__(16) unsigned short h1[64*136];
    int wave = threadIdx.x>>6, lane = threadIdx.x&63;
    int quad = lane>>4, l16 = lane&15;
    int wrow = blockIdx.x*64 + wave*16;
    const float* cg = cg2 + (size_t)(blockIdx.x>>3)*128;
    floatx4 acc[8];
    #pragma unroll
    for (int t=0;t<8;t++){
        #pragma unroll
        for(int r=0;r<4;r++) acc[t][r]=0.f;
    }
    #pragma unroll
    for (int ks=0; ks<4; ks++){
        int koff = ks*32 + quad*8;
        short8 a = *(const short8*)(A + (size_t)(wrow+l16)*128 + koff);
        #pragma unroll
        for (int t=0;t<8;t++){
            short8 b = *(const short8*)(W1t + (size_t)(t*16+l16)*128 + koff);
            acc[t] = __builtin_amdgcn_mfma_f32_16x16x32_bf16(a,b,acc[t],0,0,0);
        }
    }
    float dg[4];
    #pragma unroll
    for (int r=0;r<4;r++) dg[r] = degf[wrow + quad*4 + r];
    #pragma unroll
    for (int t=0;t<8;t++){
        int col = t*16+l16;
        float bv = b1[col];
        float cv = cg[col];
        #pragma unroll
        for (int r=0;r<4;r++){
            float v = acc[t][r] + bv + dg[r]*cv;
            v = v > 0.f ? v : 0.f;
            h1[(wave*16 + quad*4 + r)*136 + col] = f2bf(v);
        }
    }
    __syncthreads();
    floatx4 acc2[8];
    #pragma unroll
    for (int t=0;t<8;t++){
        #pragma unroll
        for(int r=0;r<4;r++) acc2[t][r]=0.f;
    }
    #pragma unroll
    for (int ks=0; ks<4; ks++){
        int koff = ks*32 + quad*8;
        short8 a = *(const short8*)(&h1[(wave*16 + l16)*136 + koff]);
        #pragma unroll
        for (int t=0;t<8;t++){
            short8 b = *(const short8*)(W2t + (size_t)(t*16+l16)*128 + koff);
            acc2[t] = __builtin_amdgcn_mfma_f32_16x16x32_bf16(a,b,acc2[t],0,0,0);
        }
    }
    float ss[4] = {0.f,0.f,0.f,0.f};
    #pragma unroll
    for (int t=0;t<8;t++){
        int col = t*16+l16;
        float bv = b2[col];
        #pragma unroll
        for (int r=0;r<4;r++){
            float v = acc2[t][r] + bv;
            out[(size_t)(wrow + quad*4 + r)*128 + col] = f2bf(v);
            ss[r] += v*v;
        }
    }
    #pragma unroll
    for (int r=0;r<4;r++){
        #pragma unroll
        for (int o=1;o<16;o<<=1) ss[r] += __shfl_xor(ss[r], o);
    }
    if (l16==0){
        #pragma unroll
        for (int r=0;r<4;r++) nrm2[wrow + quad*4 + r] = ss[r];
    }
}

// ---- per-graph sum of h_g (bf16) ----
__global__ __launch_bounds__(128) void k_hgsum(const unsigned short* __restrict__ h_g,
                                               float* __restrict__ hgs){
    int g = blockIdx.x, d = threadIdx.x;
    float acc=0;
    const unsigned short* p = h_g + (size_t)g*NPG*128 + d;
    for (int n=0;n<NPG;n++) acc += bf2f(p[(size_t)n*128]);
    hgs[g*128+d] = acc;
}

// ---- predictor (fp32) ----
__global__ __launch_bounds__(128) void k_pred(const float* __restrict__ hgs,
        const float* __restrict__ Wp1, const float* __restrict__ bp1,
        const float* __restrict__ Wp2, const float* __restrict__ bp2,
        float* __restrict__ y){
    int g=blockIdx.x, j=threadIdx.x;
    __shared__ float row[128];
    __shared__ float red[128];
    row[j] = hgs[g*128+j];
    __syncthreads();
    float acc = bp1[j];
    for (int k=0;k<128;k++) acc += row[k]*Wp1[k*128+j];
    acc = fmaxf(acc, 0.f);
    red[j] = acc * Wp2[j];
    __syncthreads();
    for (int s=64;s>0;s>>=1){ if (j<s) red[j]+=red[j+s]; __syncthreads(); }
    if (j==0) y[g] = red[0] + bp2[0];
}

extern "C" void kernel_launch(void* const* d_in, const int* in_sizes, int n_in,
                              void* d_out, int out_size, void* d_ws, size_t ws_size,
                              hipStream_t stream) {
    const float* X    = (const float*)d_in[0];
    const float* X_q  = (const float*)d_in[1];
    const int* g_src = (const int*)d_in[2];
    const int* g_dst = (const int*)d_in[3];
    const int* q_src = (const int*)d_in[5];
    const int* q_dst = (const int*)d_in[6];
    const float* Wg   = (const float*)d_in[8];
    const float* bg   = (const float*)d_in[9];
    const float* Wq   = (const float*)d_in[10];
    const float* bq   = (const float*)d_in[11];
    const float* betas_g = (const float*)d_in[12];
    const float* betas_q = (const float*)d_in[13];
    const float* W1r  = (const float*)d_in[14];
    const float* b1r  = (const float*)d_in[15];
    const float* W2r  = (const float*)d_in[16];
    const float* b2r  = (const float*)d_in[17];
    const float* Wp1  = (const float*)d_in[18];
    const float* bp1  = (const float*)d_in[19];
    const float* Wp2  = (const float*)d_in[20];
    const float* bp2  = (const float*)d_in[21];

    uint8_t* w = (uint8_t*)d_ws;
    unsigned short* h_g  = (unsigned short*)w;    w += (size_t)NG*128*2;
    unsigned short* h_q  = (unsigned short*)w;    w += (size_t)NQ*128*2;
    unsigned short* aout = (unsigned short*)w;    w += (size_t)NG*128*2;
    float* nrm2  = (float*)w;                     w += (size_t)NG*4;
    float* degf  = (float*)w;                     w += (size_t)NG*4;
    float* hqa   = (float*)w;                     w += (size_t)B_*128*4;
    float* Qg    = (float*)w;                     w += (size_t)B_*4*4;
    float* cg2   = (float*)w;                     w += (size_t)B_*128*4;
    float* hgs   = (float*)w;                     w += (size_t)B_*128*4;
    unsigned short* WgT   = (unsigned short*)w;   w += 8192*2;
    unsigned short* WqT   = (unsigned short*)w;   w += 8192*2;
    unsigned short* W1aT  = (unsigned short*)w;   w += 2*16384*2;
    unsigned short* W2rT  = (unsigned short*)w;   w += 2*16384*2;
    unsigned short* srcl_g = (unsigned short*)w;  w += (size_t)B_*EPG*2;
    unsigned short* dstl_g = (unsigned short*)w;  w += (size_t)B_*EPG*2;
    unsigned short* csr_g  = (unsigned short*)w;  w += (size_t)B_*EPG*2;
    int* off_g = (int*)w;                         w += (size_t)B_*NPG*4;
    int* cnt_g = (int*)w;                         w += (size_t)B_*NPG*4;

    k_transpose<<<320,256,0,stream>>>(Wg,Wq,W1r,W2r,WgT,WqT,W1aT,W2rT);
    k_csr<<<B_,256,0,stream>>>(g_src,g_dst,srcl_g,dstl_g,csr_g,off_g,cnt_g,degf);
    k_proj<<<NG/64,256,0,stream>>>(X,   WgT, bg, h_g, nrm2);
    k_proj<<<NQ/64,256,0,stream>>>(X_q, WqT, bq, h_q, nullptr);
    for (int l=0;l<L_;l++){
        k_qagnn<<<B_,128,0,stream>>>(h_q, q_src, q_dst, betas_q + l, hqa, Qg);
        k_cvec<<<B_,128,0,stream>>>(hqa, W1r + l*32768, cg2);
        k_gagnn<<<B_,1024,0,stream>>>(h_g, nrm2, Qg, srcl_g, dstl_g, csr_g, off_g,
                                      cnt_g, betas_g + l, aout);
        k_mlp<<<NG/64,256,0,stream>>>(aout, W1aT + l*16384, b1r + l*128, cg2, degf,
                                      W2rT + l*16384, b2r + l*128, h_g, nrm2);
    }
    k_hgsum<<<B_,128,0,stream>>>(h_g, hgs);
    k_pred<<<B_,128,0,stream>>>(hgs, Wp1, bp1, Wp2, bp2, (float*)d_out);
}